// Round 1
// baseline (722.719 us; speedup 1.0000x reference)
//
#include <hip/hip_runtime.h>
#include <hip/hip_bf16.h>

typedef __bf16 bf16x8 __attribute__((ext_vector_type(8)));
typedef __bf16 bf16x4 __attribute__((ext_vector_type(4)));
typedef float  f32x4  __attribute__((ext_vector_type(4)));

#define T_TOK    8192
#define D_DIM    1024
#define H_DIM    2048
#define E_NUM    8
#define MAX_MB   136      // sum ceil(n_e/128) <= 8 + 16384/128 = 136
#define MAX_ROWS 17408    // 136*128

// ---- workspace layout (bytes) ----
#define OFF_CNT     0
#define OFF_CURSOR  64
#define OFF_OFFP    256
#define OFF_MBTOT   512
#define OFF_MB2E    1024
#define OFF_MBROW0  2048
#define OFF_TOPKE   4096            // 16384 ints  -> ends 69632
#define OFF_TOPKS   69632           // 16384 float -> ends 135168
#define OFF_TOK     135168          // 17408 ints  -> ends 204800
#define OFF_GATE    204800          // 17408 float -> ends 274432
#define OFF_XB      (1u<<20)                    // 8192*1024*2  = 16 MiB -> ends 17825792
#define OFF_W1T     (18u*1024*1024)             // 8*2048*1024*2 = 32 MiB -> ends 50 MiB
#define OFF_W2T     (50u*1024*1024)             // 8*1024*2048*2 = 32 MiB -> ends 82 MiB
#define OFF_HBUF    (82u*1024*1024)             // 17408*2048*2  = 68 MiB -> ends 150 MiB

__device__ __forceinline__ void gload_lds16(const void* g, void* l) {
    __builtin_amdgcn_global_load_lds(
        (const __attribute__((address_space(1))) void*)g,
        (__attribute__((address_space(3))) void*)l, 16, 0, 0);
}

// ---------------- router: logits -> top2 -> normalized gates ----------------
__global__ __launch_bounds__(256) void k_router(
    const float* __restrict__ x, const float* __restrict__ Wg,
    int* __restrict__ topk_e, float* __restrict__ topk_s, int* __restrict__ cnt)
{
    const int wave = threadIdx.x >> 6, lane = threadIdx.x & 63;
    const int t = blockIdx.x * 4 + wave;
    const float* xr = x + (size_t)t * D_DIM;

    float acc[E_NUM];
#pragma unroll
    for (int e = 0; e < E_NUM; ++e) acc[e] = 0.f;

#pragma unroll
    for (int j = 0; j < 4; ++j) {
        int d = lane * 4 + j * 256;
        float4 xv = *(const float4*)(xr + d);
        const float* xvf = (const float*)&xv;
#pragma unroll
        for (int u = 0; u < 4; ++u) {
            float xd = xvf[u];
            const float* wrow = Wg + (size_t)(d + u) * E_NUM;
#pragma unroll
            for (int e = 0; e < E_NUM; ++e) acc[e] += xd * wrow[e];
        }
    }
#pragma unroll
    for (int off = 32; off >= 1; off >>= 1)
#pragma unroll
        for (int e = 0; e < E_NUM; ++e) acc[e] += __shfl_xor(acc[e], off, 64);

    if (lane == 0) {
        int e0 = 0; float v0 = acc[0];
#pragma unroll
        for (int e = 1; e < E_NUM; ++e) if (acc[e] > v0) { v0 = acc[e]; e0 = e; }
        int e1 = -1; float v1 = -1e30f;
#pragma unroll
        for (int e = 0; e < E_NUM; ++e) if (e != e0 && acc[e] > v1) { v1 = acc[e]; e1 = e; }
        float s0 = 1.f / (1.f + __expf(v1 - v0));  // = p0/(p0+p1)
        float s1 = 1.f - s0;
        topk_e[t*2+0] = e0; topk_e[t*2+1] = e1;
        topk_s[t*2+0] = s0; topk_s[t*2+1] = s1;
        atomicAdd(&cnt[e0], 1); atomicAdd(&cnt[e1], 1);
    }
}

// ---------------- offsets + M-block tables (trivial serial) ----------------
__global__ void k_offsets(const int* __restrict__ cnt, int* __restrict__ off_p,
                          int* __restrict__ mbTot, int* __restrict__ mb2e,
                          int* __restrict__ mbrow0)
{
    if (threadIdx.x == 0 && blockIdx.x == 0) {
        int row = 0, mb = 0;
        for (int e = 0; e < E_NUM; ++e) {
            off_p[e] = row;
            int nb = (cnt[e] + 127) >> 7;
            for (int b = 0; b < nb; ++b) { mb2e[mb] = e; mbrow0[mb] = row + b*128; ++mb; }
            row += nb * 128;
        }
        mbTot[0] = mb;
    }
}

// ---------------- scatter tokens into per-expert padded row space ----------------
__global__ __launch_bounds__(256) void k_scatter(
    const int* __restrict__ topk_e, const float* __restrict__ topk_s,
    const int* __restrict__ off_p, int* __restrict__ cursor,
    int* __restrict__ tok, float* __restrict__ gate)
{
    int t = blockIdx.x * 256 + threadIdx.x;
#pragma unroll
    for (int k = 0; k < 2; ++k) {
        int e = topk_e[t*2+k];
        float s = topk_s[t*2+k];
        int pos = atomicAdd(&cursor[e], 1);
        int r = off_p[e] + pos;
        tok[r] = t; gate[r] = s;
    }
}

// ---------------- x fp32 -> bf16 ----------------
__global__ __launch_bounds__(256) void k_cvt_x(const float4* __restrict__ x,
                                               bf16x4* __restrict__ xb)
{
    int i = blockIdx.x * 256 + threadIdx.x;     // i-th group of 4 floats
    float4 v = x[i];
    bf16x4 o = { (__bf16)v.x, (__bf16)v.y, (__bf16)v.z, (__bf16)v.w };
    xb[i] = o;
}

// ---------------- transpose+convert: in [E][R][C] f32 -> out [E][C][R] bf16 ----------------
__global__ __launch_bounds__(256) void k_transpose(
    const float* __restrict__ in, __bf16* __restrict__ out, int R, int C)
{
    __shared__ float tile[64][65];
    const int e = blockIdx.z;
    const float* inp = in + (size_t)e * R * C;
    __bf16* outp = out + (size_t)e * R * C;
    const int r0 = blockIdx.x * 64, c0 = blockIdx.y * 64;
    const int c = threadIdx.x & 63, rr = threadIdx.x >> 6;
#pragma unroll
    for (int i = 0; i < 16; ++i) {
        int r = rr + i * 4;
        tile[r][c] = inp[(size_t)(r0 + r) * C + c0 + c];
    }
    __syncthreads();
#pragma unroll
    for (int i = 0; i < 16; ++i) {
        int cc = rr + i * 4;
        outp[(size_t)(c0 + cc) * R + r0 + c] = (__bf16)tile[c][cc];
    }
}

// ---------------- GEMM1: h = relu(gather(x) @ W1[e] + b1[e]) -> hbuf (bf16) ----------------
// A: xb gathered rows [128 x K=1024]; B: W1T[e] rows n (K-contig) [128 x 1024]
__global__ __launch_bounds__(256) void k_gemm1(
    const __bf16* __restrict__ xb, const __bf16* __restrict__ W1T,
    const float* __restrict__ b1, const int* __restrict__ tok,
    const int* __restrict__ mb2e, const int* __restrict__ mbrow0,
    const int* __restrict__ mbTot, __bf16* __restrict__ hbuf)
{
    if ((int)blockIdx.x >= *mbTot) return;
    const int e    = mb2e[blockIdx.x];
    const int row0 = mbrow0[blockIdx.x];
    const int n0   = blockIdx.y * 128;

    __shared__ __align__(16) char smem[16384];   // A: [0,8192) = [128][32]bf16, B: [8192,16384)

    const int tid = threadIdx.x;
    const int w = tid >> 6, l = tid & 63;
    const int part = l & 3;

    const __bf16* Wb = W1T + (size_t)e * (size_t)(H_DIM * D_DIM);
    const __bf16* gA[2]; const __bf16* gB[2];
#pragma unroll
    for (int j = 0; j < 2; ++j) {
        int rr = (w*2 + j) * 16 + (l >> 2);        // 0..127
        int t  = tok[row0 + rr];
        gA[j] = xb + (size_t)t * D_DIM + part * 8;
        gB[j] = Wb + (size_t)(n0 + rr) * D_DIM + part * 8;
    }
    char* ldsA0 = smem + (w*2 + 0) * 1024;
    char* ldsA1 = smem + (w*2 + 1) * 1024;
    char* ldsB0 = smem + 8192 + (w*2 + 0) * 1024;
    char* ldsB1 = smem + 8192 + (w*2 + 1) * 1024;

    const int r = l & 15, q = l >> 4;
    const int wm = w & 1, wn = w >> 1;

    f32x4 acc[4][4];
#pragma unroll
    for (int mi = 0; mi < 4; ++mi)
#pragma unroll
        for (int ni = 0; ni < 4; ++ni) acc[mi][ni] = (f32x4){0.f, 0.f, 0.f, 0.f};

    for (int k0 = 0; k0 < D_DIM; k0 += 32) {
        gload_lds16(gA[0] + k0, ldsA0);
        gload_lds16(gA[1] + k0, ldsA1);
        gload_lds16(gB[0] + k0, ldsB0);
        gload_lds16(gB[1] + k0, ldsB1);
        __syncthreads();

        bf16x8 av[4], bv[4];
#pragma unroll
        for (int mi = 0; mi < 4; ++mi)
            av[mi] = *(const bf16x8*)(smem + ((wm*64 + mi*16 + r) * 64 + q * 16));
#pragma unroll
        for (int ni = 0; ni < 4; ++ni)
            bv[ni] = *(const bf16x8*)(smem + 8192 + ((wn*64 + ni*16 + r) * 64 + q * 16));
#pragma unroll
        for (int mi = 0; mi < 4; ++mi)
#pragma unroll
            for (int ni = 0; ni < 4; ++ni)
                acc[mi][ni] = __builtin_amdgcn_mfma_f32_16x16x32_bf16(av[mi], bv[ni], acc[mi][ni], 0, 0, 0);
        __syncthreads();
    }

    const float* b1e = b1 + (size_t)e * H_DIM;
    float bb[4];
#pragma unroll
    for (int ni = 0; ni < 4; ++ni) bb[ni] = b1e[n0 + wn*64 + ni*16 + r];
#pragma unroll
    for (int mi = 0; mi < 4; ++mi)
#pragma unroll
        for (int reg = 0; reg < 4; ++reg) {
            int m = wm*64 + mi*16 + q*4 + reg;
            __bf16* hrow = hbuf + (size_t)(row0 + m) * H_DIM + n0 + wn*64;
#pragma unroll
            for (int ni = 0; ni < 4; ++ni) {
                float v = acc[mi][ni][reg] + bb[ni];
                hrow[ni*16 + r] = (__bf16)fmaxf(v, 0.f);
            }
        }
}

// ---------------- GEMM2: out += gate * (hbuf @ W2[e] + b2[e]) via atomics ----------------
__global__ __launch_bounds__(256) void k_gemm2(
    const __bf16* __restrict__ hbuf, const __bf16* __restrict__ W2T,
    const float* __restrict__ b2, const int* __restrict__ tok,
    const float* __restrict__ gate, const int* __restrict__ mb2e,
    const int* __restrict__ mbrow0, const int* __restrict__ mbTot,
    float* __restrict__ out)
{
    if ((int)blockIdx.x >= *mbTot) return;
    const int e    = mb2e[blockIdx.x];
    const int row0 = mbrow0[blockIdx.x];
    const int n0   = blockIdx.y * 128;

    __shared__ __align__(16) char smem[16384];

    const int tid = threadIdx.x;
    const int w = tid >> 6, l = tid & 63;
    const int part = l & 3;

    const __bf16* Wb = W2T + (size_t)e * (size_t)(D_DIM * H_DIM);
    const __bf16* gA[2]; const __bf16* gB[2];
#pragma unroll
    for (int j = 0; j < 2; ++j) {
        int rr = (w*2 + j) * 16 + (l >> 2);
        gA[j] = hbuf + (size_t)(row0 + rr) * H_DIM + part * 8;
        gB[j] = Wb + (size_t)(n0 + rr) * H_DIM + part * 8;
    }
    char* ldsA0 = smem + (w*2 + 0) * 1024;
    char* ldsA1 = smem + (w*2 + 1) * 1024;
    char* ldsB0 = smem + 8192 + (w*2 + 0) * 1024;
    char* ldsB1 = smem + 8192 + (w*2 + 1) * 1024;

    const int r = l & 15, q = l >> 4;
    const int wm = w & 1, wn = w >> 1;

    f32x4 acc[4][4];
#pragma unroll
    for (int mi = 0; mi < 4; ++mi)
#pragma unroll
        for (int ni = 0; ni < 4; ++ni) acc[mi][ni] = (f32x4){0.f, 0.f, 0.f, 0.f};

    for (int k0 = 0; k0 < H_DIM; k0 += 32) {
        gload_lds16(gA[0] + k0, ldsA0);
        gload_lds16(gA[1] + k0, ldsA1);
        gload_lds16(gB[0] + k0, ldsB0);
        gload_lds16(gB[1] + k0, ldsB1);
        __syncthreads();

        bf16x8 av[4], bv[4];
#pragma unroll
        for (int mi = 0; mi < 4; ++mi)
            av[mi] = *(const bf16x8*)(smem + ((wm*64 + mi*16 + r) * 64 + q * 16));
#pragma unroll
        for (int ni = 0; ni < 4; ++ni)
            bv[ni] = *(const bf16x8*)(smem + 8192 + ((wn*64 + ni*16 + r) * 64 + q * 16));
#pragma unroll
        for (int mi = 0; mi < 4; ++mi)
#pragma unroll
            for (int ni = 0; ni < 4; ++ni)
                acc[mi][ni] = __builtin_amdgcn_mfma_f32_16x16x32_bf16(av[mi], bv[ni], acc[mi][ni], 0, 0, 0);
        __syncthreads();
    }

    const float* b2e = b2 + (size_t)e * D_DIM;
    float bb[4];
#pragma unroll
    for (int ni = 0; ni < 4; ++ni) bb[ni] = b2e[n0 + wn*64 + ni*16 + r];
#pragma unroll
    for (int mi = 0; mi < 4; ++mi)
#pragma unroll
        for (int reg = 0; reg < 4; ++reg) {
            int row = row0 + wm*64 + mi*16 + q*4 + reg;
            float g = gate[row];
            if (g != 0.f) {
                float* orow = out + (size_t)tok[row] * D_DIM + n0 + wn*64;
#pragma unroll
                for (int ni = 0; ni < 4; ++ni)
                    atomicAdd(orow + ni*16 + r, g * (acc[mi][ni][reg] + bb[ni]));
            }
        }
}

extern "C" void kernel_launch(void* const* d_in, const int* in_sizes, int n_in,
                              void* d_out, int out_size, void* d_ws, size_t ws_size,
                              hipStream_t stream) {
    const float* x  = (const float*)d_in[0];
    const float* Wg = (const float*)d_in[1];
    const float* W1 = (const float*)d_in[2];
    const float* b1 = (const float*)d_in[3];
    const float* W2 = (const float*)d_in[4];
    const float* b2 = (const float*)d_in[5];
    float* out = (float*)d_out;
    char* ws = (char*)d_ws;

    int*   cnt    = (int*)  (ws + OFF_CNT);
    int*   cursor = (int*)  (ws + OFF_CURSOR);
    int*   off_p  = (int*)  (ws + OFF_OFFP);
    int*   mbTot  = (int*)  (ws + OFF_MBTOT);
    int*   mb2e   = (int*)  (ws + OFF_MB2E);
    int*   mbrow0 = (int*)  (ws + OFF_MBROW0);
    int*   topk_e = (int*)  (ws + OFF_TOPKE);
    float* topk_s = (float*)(ws + OFF_TOPKS);
    int*   tok    = (int*)  (ws + OFF_TOK);
    float* gate   = (float*)(ws + OFF_GATE);
    __bf16* xb   = (__bf16*)(ws + OFF_XB);
    __bf16* W1T  = (__bf16*)(ws + OFF_W1T);
    __bf16* W2T  = (__bf16*)(ws + OFF_W2T);
    __bf16* hbuf = (__bf16*)(ws + OFF_HBUF);

    // zero control block, tok/gate (pad rows -> tok=0, gate=0), and output
    hipMemsetAsync(ws, 0, 1024, stream);
    hipMemsetAsync(ws + OFF_TOK, 0, 274432 - OFF_TOK, stream);
    hipMemsetAsync(d_out, 0, (size_t)T_TOK * D_DIM * sizeof(float), stream);

    k_router  <<<T_TOK/4, 256, 0, stream>>>(x, Wg, topk_e, topk_s, cnt);
    k_offsets <<<1, 64, 0, stream>>>(cnt, off_p, mbTot, mb2e, mbrow0);
    k_scatter <<<T_TOK/256, 256, 0, stream>>>(topk_e, topk_s, off_p, cursor, tok, gate);
    k_cvt_x   <<<(T_TOK*D_DIM)/(256*4), 256, 0, stream>>>((const float4*)x, (bf16x4*)xb);
    k_transpose<<<dim3(D_DIM/64, H_DIM/64, E_NUM), 256, 0, stream>>>(W1, W1T, D_DIM, H_DIM);
    k_transpose<<<dim3(H_DIM/64, D_DIM/64, E_NUM), 256, 0, stream>>>(W2, W2T, H_DIM, D_DIM);

    k_gemm1<<<dim3(MAX_MB, H_DIM/128), 256, 0, stream>>>(xb, W1T, b1, tok, mb2e, mbrow0, mbTot, hbuf);
    k_gemm2<<<dim3(MAX_MB, D_DIM/128), 256, 0, stream>>>(hbuf, W2T, b2, tok, gate, mb2e, mbrow0, mbTot, out);
}

// Round 2
// 665.357 us; speedup vs baseline: 1.0862x; 1.0862x over previous
//
#include <hip/hip_runtime.h>
#include <hip/hip_bf16.h>

typedef __bf16 bf16x8 __attribute__((ext_vector_type(8)));
typedef __bf16 bf16x4 __attribute__((ext_vector_type(4)));
typedef float  f32x4  __attribute__((ext_vector_type(4)));

#define T_TOK    8192
#define D_DIM    1024
#define H_DIM    2048
#define E_NUM    8
#define MAX_MB   136      // sum ceil(n_e/128) <= 8 + 16384/128 = 136
#define MAX_ROWS 17408    // 136*128

// ---- workspace layout (bytes) ----
#define OFF_CNT     0
#define OFF_CURSOR  64
#define OFF_OFFP    256
#define OFF_MBTOT   512
#define OFF_MB2E    1024
#define OFF_MBROW0  2048
#define OFF_TOPKE   4096            // 16384 ints  -> ends 69632
#define OFF_TOPKS   69632           // 16384 float -> ends 135168
#define OFF_TOK     135168          // 17408 ints  -> ends 204800
#define OFF_ROWIDX  204800          // 16384 ints  -> ends 270336
#define OFF_XB      (1u<<20)                    // 8192*1024*2  = 16 MiB
#define OFF_W1T     (18u*1024*1024)             // 8*2048*1024*2 = 32 MiB -> ends 50 MiB
#define OFF_W2T     (50u*1024*1024)             // 8*1024*2048*2 = 32 MiB -> ends 82 MiB
#define OFF_HBUF    (82u*1024*1024)             // 17408*2048*2  = 68 MiB -> ends 150 MiB
// ybuf bf16 [17408][1024] = 34 MiB overlaid on xb+W1T (both dead after gemm1)
#define OFF_YBUF    OFF_XB

__device__ __forceinline__ void gload_lds16(const void* g, void* l) {
    __builtin_amdgcn_global_load_lds(
        (const __attribute__((address_space(1))) void*)g,
        (__attribute__((address_space(3))) void*)l, 16, 0, 0);
}

// ---------------- fused router (+ fp32->bf16 convert of x) ----------------
// 1 wave = 1 token. Wg transposed in LDS with padded stride (conflict-free).
__global__ __launch_bounds__(256) void k_router_cvt(
    const float* __restrict__ x, const float* __restrict__ Wg,
    __bf16* __restrict__ xb, int* __restrict__ topk_e, float* __restrict__ topk_s,
    int* __restrict__ cnt)
{
    __shared__ float wgT[E_NUM][1032];   // padded stride: store 2-way, load conflict-free
    const int tid = threadIdx.x;
#pragma unroll
    for (int i = 0; i < 32; ++i) {
        int f = tid + i * 256;           // coalesced read of Wg[1024][8]
        wgT[f & 7][f >> 3] = Wg[f];
    }
    __syncthreads();

    const int wave = tid >> 6, lane = tid & 63;
    const int t = blockIdx.x * 4 + wave;
    const float* xr = x + (size_t)t * D_DIM;
    __bf16* xbr = xb + (size_t)t * D_DIM;

    float acc[E_NUM];
#pragma unroll
    for (int e = 0; e < E_NUM; ++e) acc[e] = 0.f;

#pragma unroll
    for (int j = 0; j < 4; ++j) {
        const int d0 = lane * 4 + j * 256;
        float4 xv = *(const float4*)(xr + d0);
        bf16x4 o = { (__bf16)xv.x, (__bf16)xv.y, (__bf16)xv.z, (__bf16)xv.w };
        *(bf16x4*)(xbr + d0) = o;
#pragma unroll
        for (int e = 0; e < E_NUM; ++e) {
            float4 wv = *(const float4*)&wgT[e][d0];
            acc[e] += xv.x * wv.x + xv.y * wv.y + xv.z * wv.z + xv.w * wv.w;
        }
    }
#pragma unroll
    for (int off = 32; off >= 1; off >>= 1)
#pragma unroll
        for (int e = 0; e < E_NUM; ++e) acc[e] += __shfl_xor(acc[e], off, 64);

    if (lane == 0) {
        int e0 = 0; float v0 = acc[0];
#pragma unroll
        for (int e = 1; e < E_NUM; ++e) if (acc[e] > v0) { v0 = acc[e]; e0 = e; }
        int e1 = -1; float v1 = -1e30f;
#pragma unroll
        for (int e = 0; e < E_NUM; ++e) if (e != e0 && acc[e] > v1) { v1 = acc[e]; e1 = e; }
        float s0 = 1.f / (1.f + __expf(v1 - v0));  // renormalized top-2 softmax
        float s1 = 1.f - s0;
        topk_e[t*2+0] = e0; topk_e[t*2+1] = e1;
        topk_s[t*2+0] = s0; topk_s[t*2+1] = s1;
        atomicAdd(&cnt[e0], 1); atomicAdd(&cnt[e1], 1);
    }
}

// ---------------- offsets + M-block tables (trivial serial) ----------------
__global__ void k_offsets(const int* __restrict__ cnt, int* __restrict__ off_p,
                          int* __restrict__ mbTot, int* __restrict__ mb2e,
                          int* __restrict__ mbrow0)
{
    if (threadIdx.x == 0 && blockIdx.x == 0) {
        int row = 0, mb = 0;
        for (int e = 0; e < E_NUM; ++e) {
            off_p[e] = row;
            int nb = (cnt[e] + 127) >> 7;
            for (int b = 0; b < nb; ++b) { mb2e[mb] = e; mbrow0[mb] = row + b*128; ++mb; }
            row += nb * 128;
        }
        mbTot[0] = mb;
    }
}

// ---------------- scatter tokens into per-expert padded row space ----------------
__global__ __launch_bounds__(256) void k_scatter(
    const int* __restrict__ topk_e, const int* __restrict__ off_p,
    int* __restrict__ cursor, int* __restrict__ tok, int* __restrict__ rowidx)
{
    int t = blockIdx.x * 256 + threadIdx.x;
#pragma unroll
    for (int k = 0; k < 2; ++k) {
        int e = topk_e[t*2+k];
        int pos = atomicAdd(&cursor[e], 1);
        int r = off_p[e] + pos;
        tok[r] = t; rowidx[t*2+k] = r;
    }
}

// ---------------- transpose+convert: in [E][R][C] f32 -> out [E][C][R] bf16 ----------------
__global__ __launch_bounds__(256) void k_transpose(
    const float* __restrict__ in, __bf16* __restrict__ out, int R, int C)
{
    __shared__ float tile[64][65];
    const int e = blockIdx.z;
    const float* inp = in + (size_t)e * R * C;
    __bf16* outp = out + (size_t)e * R * C;
    const int r0 = blockIdx.x * 64, c0 = blockIdx.y * 64;
    const int c = threadIdx.x & 63, rr = threadIdx.x >> 6;
#pragma unroll
    for (int i = 0; i < 16; ++i) {
        int r = rr + i * 4;
        tile[r][c] = inp[(size_t)(r0 + r) * C + c0 + c];
    }
    __syncthreads();
#pragma unroll
    for (int i = 0; i < 16; ++i) {
        int cc = rr + i * 4;
        outp[(size_t)(c0 + cc) * R + r0 + c] = (__bf16)tile[c][cc];
    }
}

// ---------------- GEMM1: h = relu(gather(x) @ W1[e] + b1[e]) -> hbuf (bf16) ----------------
__global__ __launch_bounds__(256) void k_gemm1(
    const __bf16* __restrict__ xb, const __bf16* __restrict__ W1T,
    const float* __restrict__ b1, const int* __restrict__ tok,
    const int* __restrict__ mb2e, const int* __restrict__ mbrow0,
    const int* __restrict__ mbTot, __bf16* __restrict__ hbuf)
{
    if ((int)blockIdx.x >= *mbTot) return;
    const int e    = mb2e[blockIdx.x];
    const int row0 = mbrow0[blockIdx.x];
    const int n0   = blockIdx.y * 128;

    __shared__ __align__(16) char smem[16384];   // A: [0,8192) = [128][32]bf16, B: [8192,16384)

    const int tid = threadIdx.x;
    const int w = tid >> 6, l = tid & 63;
    const int part = l & 3;

    const __bf16* Wb = W1T + (size_t)e * (size_t)(H_DIM * D_DIM);
    const __bf16* gA[2]; const __bf16* gB[2];
#pragma unroll
    for (int j = 0; j < 2; ++j) {
        int rr = (w*2 + j) * 16 + (l >> 2);        // 0..127
        int t  = tok[row0 + rr];
        gA[j] = xb + (size_t)t * D_DIM + part * 8;
        gB[j] = Wb + (size_t)(n0 + rr) * D_DIM + part * 8;
    }
    char* ldsA0 = smem + (w*2 + 0) * 1024;
    char* ldsA1 = smem + (w*2 + 1) * 1024;
    char* ldsB0 = smem + 8192 + (w*2 + 0) * 1024;
    char* ldsB1 = smem + 8192 + (w*2 + 1) * 1024;

    const int r = l & 15, q = l >> 4;
    const int wm = w & 1, wn = w >> 1;

    f32x4 acc[4][4];
#pragma unroll
    for (int mi = 0; mi < 4; ++mi)
#pragma unroll
        for (int ni = 0; ni < 4; ++ni) acc[mi][ni] = (f32x4){0.f, 0.f, 0.f, 0.f};

    for (int k0 = 0; k0 < D_DIM; k0 += 32) {
        gload_lds16(gA[0] + k0, ldsA0);
        gload_lds16(gA[1] + k0, ldsA1);
        gload_lds16(gB[0] + k0, ldsB0);
        gload_lds16(gB[1] + k0, ldsB1);
        __syncthreads();

        bf16x8 av[4], bv[4];
#pragma unroll
        for (int mi = 0; mi < 4; ++mi)
            av[mi] = *(const bf16x8*)(smem + ((wm*64 + mi*16 + r) * 64 + q * 16));
#pragma unroll
        for (int ni = 0; ni < 4; ++ni)
            bv[ni] = *(const bf16x8*)(smem + 8192 + ((wn*64 + ni*16 + r) * 64 + q * 16));
#pragma unroll
        for (int mi = 0; mi < 4; ++mi)
#pragma unroll
            for (int ni = 0; ni < 4; ++ni)
                acc[mi][ni] = __builtin_amdgcn_mfma_f32_16x16x32_bf16(av[mi], bv[ni], acc[mi][ni], 0, 0, 0);
        __syncthreads();
    }

    const float* b1e = b1 + (size_t)e * H_DIM;
    float bb[4];
#pragma unroll
    for (int ni = 0; ni < 4; ++ni) bb[ni] = b1e[n0 + wn*64 + ni*16 + r];
#pragma unroll
    for (int mi = 0; mi < 4; ++mi)
#pragma unroll
        for (int reg = 0; reg < 4; ++reg) {
            int m = wm*64 + mi*16 + q*4 + reg;
            __bf16* hrow = hbuf + (size_t)(row0 + m) * H_DIM + n0 + wn*64;
#pragma unroll
            for (int ni = 0; ni < 4; ++ni) {
                float v = acc[mi][ni][reg] + bb[ni];
                hrow[ni*16 + r] = (__bf16)fmaxf(v, 0.f);
            }
        }
}

// ---------------- GEMM2: ybuf[row] = hbuf[row] @ W2[e] + b2[e]  (bf16, ungated) ----------------
__global__ __launch_bounds__(256) void k_gemm2(
    const __bf16* __restrict__ hbuf, const __bf16* __restrict__ W2T,
    const float* __restrict__ b2, const int* __restrict__ mb2e,
    const int* __restrict__ mbrow0, const int* __restrict__ mbTot,
    __bf16* __restrict__ ybuf)
{
    if ((int)blockIdx.x >= *mbTot) return;
    const int e    = mb2e[blockIdx.x];
    const int row0 = mbrow0[blockIdx.x];
    const int n0   = blockIdx.y * 128;

    __shared__ __align__(16) char smem[16384];

    const int tid = threadIdx.x;
    const int w = tid >> 6, l = tid & 63;
    const int part = l & 3;

    const __bf16* Wb = W2T + (size_t)e * (size_t)(D_DIM * H_DIM);
    const __bf16* gA[2]; const __bf16* gB[2];
#pragma unroll
    for (int j = 0; j < 2; ++j) {
        int rr = (w*2 + j) * 16 + (l >> 2);
        gA[j] = hbuf + (size_t)(row0 + rr) * H_DIM + part * 8;
        gB[j] = Wb + (size_t)(n0 + rr) * H_DIM + part * 8;
    }
    char* ldsA0 = smem + (w*2 + 0) * 1024;
    char* ldsA1 = smem + (w*2 + 1) * 1024;
    char* ldsB0 = smem + 8192 + (w*2 + 0) * 1024;
    char* ldsB1 = smem + 8192 + (w*2 + 1) * 1024;

    const int r = l & 15, q = l >> 4;
    const int wm = w & 1, wn = w >> 1;

    f32x4 acc[4][4];
#pragma unroll
    for (int mi = 0; mi < 4; ++mi)
#pragma unroll
        for (int ni = 0; ni < 4; ++ni) acc[mi][ni] = (f32x4){0.f, 0.f, 0.f, 0.f};

    for (int k0 = 0; k0 < H_DIM; k0 += 32) {
        gload_lds16(gA[0] + k0, ldsA0);
        gload_lds16(gA[1] + k0, ldsA1);
        gload_lds16(gB[0] + k0, ldsB0);
        gload_lds16(gB[1] + k0, ldsB1);
        __syncthreads();

        bf16x8 av[4], bv[4];
#pragma unroll
        for (int mi = 0; mi < 4; ++mi)
            av[mi] = *(const bf16x8*)(smem + ((wm*64 + mi*16 + r) * 64 + q * 16));
#pragma unroll
        for (int ni = 0; ni < 4; ++ni)
            bv[ni] = *(const bf16x8*)(smem + 8192 + ((wn*64 + ni*16 + r) * 64 + q * 16));
#pragma unroll
        for (int mi = 0; mi < 4; ++mi)
#pragma unroll
            for (int ni = 0; ni < 4; ++ni)
                acc[mi][ni] = __builtin_amdgcn_mfma_f32_16x16x32_bf16(av[mi], bv[ni], acc[mi][ni], 0, 0, 0);
        __syncthreads();
    }

    const float* b2e = b2 + (size_t)e * D_DIM;
    float bb[4];
#pragma unroll
    for (int ni = 0; ni < 4; ++ni) bb[ni] = b2e[n0 + wn*64 + ni*16 + r];
#pragma unroll
    for (int mi = 0; mi < 4; ++mi)
#pragma unroll
        for (int reg = 0; reg < 4; ++reg) {
            int row = row0 + wm*64 + mi*16 + q*4 + reg;
            __bf16* yrow = ybuf + (size_t)row * D_DIM + n0 + wn*64;
#pragma unroll
            for (int ni = 0; ni < 4; ++ni)
                yrow[ni*16 + r] = (__bf16)(acc[mi][ni][reg] + bb[ni]);
        }
}

// ---------------- combine: out[t] = s0*y[r0] + s1*y[r1] ----------------
__global__ __launch_bounds__(256) void k_combine(
    const __bf16* __restrict__ ybuf, const int* __restrict__ rowidx,
    const float* __restrict__ topk_s, float* __restrict__ out)
{
    const int t = blockIdx.x;
    const int d0 = threadIdx.x * 4;
    const int r0 = rowidx[t*2+0], r1 = rowidx[t*2+1];
    const float s0 = topk_s[t*2+0], s1 = topk_s[t*2+1];
    bf16x4 y0 = *(const bf16x4*)(ybuf + (size_t)r0 * D_DIM + d0);
    bf16x4 y1 = *(const bf16x4*)(ybuf + (size_t)r1 * D_DIM + d0);
    float4 o;
    o.x = s0 * (float)y0[0] + s1 * (float)y1[0];
    o.y = s0 * (float)y0[1] + s1 * (float)y1[1];
    o.z = s0 * (float)y0[2] + s1 * (float)y1[2];
    o.w = s0 * (float)y0[3] + s1 * (float)y1[3];
    *(float4*)(out + (size_t)t * D_DIM + d0) = o;
}

extern "C" void kernel_launch(void* const* d_in, const int* in_sizes, int n_in,
                              void* d_out, int out_size, void* d_ws, size_t ws_size,
                              hipStream_t stream) {
    const float* x  = (const float*)d_in[0];
    const float* Wg = (const float*)d_in[1];
    const float* W1 = (const float*)d_in[2];
    const float* b1 = (const float*)d_in[3];
    const float* W2 = (const float*)d_in[4];
    const float* b2 = (const float*)d_in[5];
    float* out = (float*)d_out;
    char* ws = (char*)d_ws;

    int*   cnt    = (int*)  (ws + OFF_CNT);
    int*   cursor = (int*)  (ws + OFF_CURSOR);
    int*   off_p  = (int*)  (ws + OFF_OFFP);
    int*   mbTot  = (int*)  (ws + OFF_MBTOT);
    int*   mb2e   = (int*)  (ws + OFF_MB2E);
    int*   mbrow0 = (int*)  (ws + OFF_MBROW0);
    int*   topk_e = (int*)  (ws + OFF_TOPKE);
    float* topk_s = (float*)(ws + OFF_TOPKS);
    int*   tok    = (int*)  (ws + OFF_TOK);
    int*   rowidx = (int*)  (ws + OFF_ROWIDX);
    __bf16* xb   = (__bf16*)(ws + OFF_XB);
    __bf16* W1T  = (__bf16*)(ws + OFF_W1T);
    __bf16* W2T  = (__bf16*)(ws + OFF_W2T);
    __bf16* hbuf = (__bf16*)(ws + OFF_HBUF);
    __bf16* ybuf = (__bf16*)(ws + OFF_YBUF);

    // zero control block + tok (pad rows -> tok=0). rowidx fully written by scatter.
    hipMemsetAsync(ws, 0, 1024, stream);
    hipMemsetAsync(ws + OFF_TOK, 0, MAX_ROWS * sizeof(int), stream);

    k_router_cvt<<<T_TOK/4, 256, 0, stream>>>(x, Wg, xb, topk_e, topk_s, cnt);
    k_offsets   <<<1, 64, 0, stream>>>(cnt, off_p, mbTot, mb2e, mbrow0);
    k_scatter   <<<T_TOK/256, 256, 0, stream>>>(topk_e, off_p, cursor, tok, rowidx);
    k_transpose <<<dim3(D_DIM/64, H_DIM/64, E_NUM), 256, 0, stream>>>(W1, W1T, D_DIM, H_DIM);
    k_transpose <<<dim3(H_DIM/64, D_DIM/64, E_NUM), 256, 0, stream>>>(W2, W2T, H_DIM, D_DIM);

    k_gemm1<<<dim3(MAX_MB, H_DIM/128), 256, 0, stream>>>(xb, W1T, b1, tok, mb2e, mbrow0, mbTot, hbuf);
    k_gemm2<<<dim3(MAX_MB, D_DIM/128), 256, 0, stream>>>(hbuf, W2T, b2, mb2e, mbrow0, mbTot, ybuf);
    k_combine<<<T_TOK, 256, 0, stream>>>(ybuf, rowidx, topk_s, out);
}

// Round 3
// 437.839 us; speedup vs baseline: 1.6506x; 1.5196x over previous
//
#include <hip/hip_runtime.h>
#include <hip/hip_bf16.h>

typedef __bf16 bf16x8 __attribute__((ext_vector_type(8)));
typedef __bf16 bf16x4 __attribute__((ext_vector_type(4)));
typedef float  f32x4  __attribute__((ext_vector_type(4)));

#define T_TOK    8192
#define D_DIM    1024
#define H_DIM    2048
#define E_NUM    8
#define MAX_MB   136      // sum ceil(n_e/128) <= 8 + 16384/128 = 136
#define MAX_ROWS 17408    // 136*128

// ---- workspace layout (bytes) ----
#define OFF_MBTOT   512
#define OFF_MB2E    1024
#define OFF_MBROW0  2048
#define OFF_TOPKE   4096            // 16384 ints  -> ends 69632
#define OFF_TOPKS   69632           // 16384 float -> ends 135168
#define OFF_TOK     135168          // 17408 ints  -> ends 204800
#define OFF_ROWIDX  204800          // 16384 ints  -> ends 270336
#define OFF_XB      (1u<<20)                    // 8192*1024*2  = 16 MiB
#define OFF_W1T     (18u*1024*1024)             // 8*2048*1024*2 = 32 MiB -> ends 50 MiB
#define OFF_W2T     (50u*1024*1024)             // 8*1024*2048*2 = 32 MiB -> ends 82 MiB
#define OFF_HBUF    (82u*1024*1024)             // 17408*2048*2  = 68 MiB -> ends 150 MiB
// ybuf bf16 [17408][1024] = 34 MiB overlaid on xb+W1T (both dead after gemm1)
#define OFF_YBUF    OFF_XB

__device__ __forceinline__ void gload_lds16(const void* g, void* l) {
    __builtin_amdgcn_global_load_lds(
        (const __attribute__((address_space(1))) void*)g,
        (__attribute__((address_space(3))) void*)l, 16, 0, 0);
}

// ---------------- fused router (+ fp32->bf16 convert of x), NO atomics ----------------
__global__ __launch_bounds__(256) void k_router_cvt(
    const float* __restrict__ x, const float* __restrict__ Wg,
    __bf16* __restrict__ xb, int* __restrict__ topk_e, float* __restrict__ topk_s)
{
    __shared__ float wgT[E_NUM][1032];   // padded stride
    const int tid = threadIdx.x;
#pragma unroll
    for (int i = 0; i < 32; ++i) {
        int f = tid + i * 256;           // coalesced read of Wg[1024][8]
        wgT[f & 7][f >> 3] = Wg[f];
    }
    __syncthreads();

    const int wave = tid >> 6, lane = tid & 63;
    const int t = blockIdx.x * 4 + wave;
    const float* xr = x + (size_t)t * D_DIM;
    __bf16* xbr = xb + (size_t)t * D_DIM;

    float acc[E_NUM];
#pragma unroll
    for (int e = 0; e < E_NUM; ++e) acc[e] = 0.f;

#pragma unroll
    for (int j = 0; j < 4; ++j) {
        const int d0 = lane * 4 + j * 256;
        float4 xv = *(const float4*)(xr + d0);
        bf16x4 o = { (__bf16)xv.x, (__bf16)xv.y, (__bf16)xv.z, (__bf16)xv.w };
        *(bf16x4*)(xbr + d0) = o;
#pragma unroll
        for (int e = 0; e < E_NUM; ++e) {
            float4 wv = *(const float4*)&wgT[e][d0];
            acc[e] += xv.x * wv.x + xv.y * wv.y + xv.z * wv.z + xv.w * wv.w;
        }
    }
#pragma unroll
    for (int off = 32; off >= 1; off >>= 1)
#pragma unroll
        for (int e = 0; e < E_NUM; ++e) acc[e] += __shfl_xor(acc[e], off, 64);

    if (lane == 0) {
        int e0 = 0; float v0 = acc[0];
#pragma unroll
        for (int e = 1; e < E_NUM; ++e) if (acc[e] > v0) { v0 = acc[e]; e0 = e; }
        int e1 = -1; float v1 = -1e30f;
#pragma unroll
        for (int e = 0; e < E_NUM; ++e) if (e != e0 && acc[e] > v1) { v1 = acc[e]; e1 = e; }
        float s0 = 1.f / (1.f + __expf(v1 - v0));  // renormalized top-2 softmax
        float s1 = 1.f - s0;
        topk_e[t*2+0] = e0; topk_e[t*2+1] = e1;
        topk_s[t*2+0] = s0; topk_s[t*2+1] = s1;
    }
}

// ---------------- single-block counting sort: counts, offsets, mb tables, tok, rowidx ----------------
// 512 threads = 8 waves. Zero global atomics; deterministic placement.
#define SORT_T 256
__global__ __launch_bounds__(512) void k_sort(
    const int* __restrict__ topk_e,
    int* __restrict__ mbTot, int* __restrict__ mb2e, int* __restrict__ mbrow0,
    int* __restrict__ tok, int* __restrict__ rowidx)
{
    __shared__ int lcnt[E_NUM][SORT_T];   // per-thread exclusive offsets after scan
    __shared__ int base[E_NUM];           // padded global base row per expert
    __shared__ int etot[E_NUM];
    const int tid = threadIdx.x;

    // phase 1: per-thread histogram of 64 entries each (16384 total)
    if (tid < SORT_T) {
        int c[E_NUM];
#pragma unroll
        for (int e = 0; e < E_NUM; ++e) c[e] = 0;
        const int4* p = (const int4*)(topk_e + tid * 64);
#pragma unroll
        for (int i = 0; i < 16; ++i) {
            int4 v = p[i];
            c[v.x]++; c[v.y]++; c[v.z]++; c[v.w]++;
        }
#pragma unroll
        for (int e = 0; e < E_NUM; ++e) lcnt[e][tid] = c[e];
    }
    __syncthreads();

    // phase 2: wave w does exclusive scan over expert w's 256 thread-counts
    {
        const int w = tid >> 6, l = tid & 63;
        int v0 = lcnt[w][l*4+0], v1 = lcnt[w][l*4+1], v2 = lcnt[w][l*4+2], v3 = lcnt[w][l*4+3];
        int s = v0 + v1 + v2 + v3;
        int inc = s;
#pragma unroll
        for (int off = 1; off < 64; off <<= 1) {
            int o = __shfl_up(inc, off, 64);
            if (l >= off) inc += o;
        }
        int exc = inc - s;
        lcnt[w][l*4+0] = exc;
        lcnt[w][l*4+1] = exc + v0;
        lcnt[w][l*4+2] = exc + v0 + v1;
        lcnt[w][l*4+3] = exc + v0 + v1 + v2;
        if (l == 63) etot[w] = inc;
    }
    __syncthreads();

    // phase 3: serial (8 experts) base rows + M-block tables
    if (tid == 0) {
        int row = 0, mb = 0;
        for (int e = 0; e < E_NUM; ++e) {
            base[e] = row;
            int nb = (etot[e] + 127) >> 7;
            for (int b = 0; b < nb; ++b) { mb2e[mb] = e; mbrow0[mb] = row + b*128; ++mb; }
            row += nb * 128;
        }
        mbTot[0] = mb;
    }
    __syncthreads();

    // phase 4: placement
    if (tid < SORT_T) {
        int c[E_NUM];
#pragma unroll
        for (int e = 0; e < E_NUM; ++e) c[e] = base[e] + lcnt[e][tid];
        const int4* p = (const int4*)(topk_e + tid * 64);
#pragma unroll
        for (int i = 0; i < 16; ++i) {
            int4 v = p[i];
            int j0 = tid * 64 + i * 4;
            int r;
            r = c[v.x]++; tok[r] = (j0+0) >> 1; rowidx[j0+0] = r;
            r = c[v.y]++; tok[r] = (j0+1) >> 1; rowidx[j0+1] = r;
            r = c[v.z]++; tok[r] = (j0+2) >> 1; rowidx[j0+2] = r;
            r = c[v.w]++; tok[r] = (j0+3) >> 1; rowidx[j0+3] = r;
        }
    }
}

// ---------------- transpose+convert: in [E][R][C] f32 -> out [E][C][R] bf16 ----------------
__global__ __launch_bounds__(256) void k_transpose(
    const float* __restrict__ in, __bf16* __restrict__ out, int R, int C)
{
    __shared__ float tile[64][65];
    const int e = blockIdx.z;
    const float* inp = in + (size_t)e * R * C;
    __bf16* outp = out + (size_t)e * R * C;
    const int r0 = blockIdx.x * 64, c0 = blockIdx.y * 64;
    const int c = threadIdx.x & 63, rr = threadIdx.x >> 6;
#pragma unroll
    for (int i = 0; i < 16; ++i) {
        int r = rr + i * 4;
        tile[r][c] = inp[(size_t)(r0 + r) * C + c0 + c];
    }
    __syncthreads();
#pragma unroll
    for (int i = 0; i < 16; ++i) {
        int cc = rr + i * 4;
        outp[(size_t)(c0 + cc) * R + r0 + c] = (__bf16)tile[c][cc];
    }
}

// ---------------- GEMM1: h = relu(gather(x) @ W1[e] + b1[e]) -> hbuf (bf16) ----------------
__global__ __launch_bounds__(256) void k_gemm1(
    const __bf16* __restrict__ xb, const __bf16* __restrict__ W1T,
    const float* __restrict__ b1, const int* __restrict__ tok,
    const int* __restrict__ mb2e, const int* __restrict__ mbrow0,
    const int* __restrict__ mbTot, __bf16* __restrict__ hbuf)
{
    if ((int)blockIdx.x >= *mbTot) return;
    const int e    = mb2e[blockIdx.x];
    const int row0 = mbrow0[blockIdx.x];
    const int n0   = blockIdx.y * 128;

    __shared__ __align__(16) char smem[16384];   // A: [0,8192) = [128][32]bf16, B: [8192,16384)

    const int tid = threadIdx.x;
    const int w = tid >> 6, l = tid & 63;
    const int part = l & 3;

    const __bf16* Wb = W1T + (size_t)e * (size_t)(H_DIM * D_DIM);
    const __bf16* gA[2]; const __bf16* gB[2];
#pragma unroll
    for (int j = 0; j < 2; ++j) {
        int rr = (w*2 + j) * 16 + (l >> 2);        // 0..127
        int t  = tok[row0 + rr];
        gA[j] = xb + (size_t)t * D_DIM + part * 8;
        gB[j] = Wb + (size_t)(n0 + rr) * D_DIM + part * 8;
    }
    char* ldsA0 = smem + (w*2 + 0) * 1024;
    char* ldsA1 = smem + (w*2 + 1) * 1024;
    char* ldsB0 = smem + 8192 + (w*2 + 0) * 1024;
    char* ldsB1 = smem + 8192 + (w*2 + 1) * 1024;

    const int r = l & 15, q = l >> 4;
    const int wm = w & 1, wn = w >> 1;

    f32x4 acc[4][4];
#pragma unroll
    for (int mi = 0; mi < 4; ++mi)
#pragma unroll
        for (int ni = 0; ni < 4; ++ni) acc[mi][ni] = (f32x4){0.f, 0.f, 0.f, 0.f};

    for (int k0 = 0; k0 < D_DIM; k0 += 32) {
        gload_lds16(gA[0] + k0, ldsA0);
        gload_lds16(gA[1] + k0, ldsA1);
        gload_lds16(gB[0] + k0, ldsB0);
        gload_lds16(gB[1] + k0, ldsB1);
        __syncthreads();

        bf16x8 av[4], bv[4];
#pragma unroll
        for (int mi = 0; mi < 4; ++mi)
            av[mi] = *(const bf16x8*)(smem + ((wm*64 + mi*16 + r) * 64 + q * 16));
#pragma unroll
        for (int ni = 0; ni < 4; ++ni)
            bv[ni] = *(const bf16x8*)(smem + 8192 + ((wn*64 + ni*16 + r) * 64 + q * 16));
#pragma unroll
        for (int mi = 0; mi < 4; ++mi)
#pragma unroll
            for (int ni = 0; ni < 4; ++ni)
                acc[mi][ni] = __builtin_amdgcn_mfma_f32_16x16x32_bf16(av[mi], bv[ni], acc[mi][ni], 0, 0, 0);
        __syncthreads();
    }

    const float* b1e = b1 + (size_t)e * H_DIM;
    float bb[4];
#pragma unroll
    for (int ni = 0; ni < 4; ++ni) bb[ni] = b1e[n0 + wn*64 + ni*16 + r];
#pragma unroll
    for (int mi = 0; mi < 4; ++mi)
#pragma unroll
        for (int reg = 0; reg < 4; ++reg) {
            int m = wm*64 + mi*16 + q*4 + reg;
            __bf16* hrow = hbuf + (size_t)(row0 + m) * H_DIM + n0 + wn*64;
#pragma unroll
            for (int ni = 0; ni < 4; ++ni) {
                float v = acc[mi][ni][reg] + bb[ni];
                hrow[ni*16 + r] = (__bf16)fmaxf(v, 0.f);
            }
        }
}

// ---------------- GEMM2: ybuf[row] = hbuf[row] @ W2[e] + b2[e]  (bf16, ungated) ----------------
__global__ __launch_bounds__(256) void k_gemm2(
    const __bf16* __restrict__ hbuf, const __bf16* __restrict__ W2T,
    const float* __restrict__ b2, const int* __restrict__ mb2e,
    const int* __restrict__ mbrow0, const int* __restrict__ mbTot,
    __bf16* __restrict__ ybuf)
{
    if ((int)blockIdx.x >= *mbTot) return;
    const int e    = mb2e[blockIdx.x];
    const int row0 = mbrow0[blockIdx.x];
    const int n0   = blockIdx.y * 128;

    __shared__ __align__(16) char smem[16384];

    const int tid = threadIdx.x;
    const int w = tid >> 6, l = tid & 63;
    const int part = l & 3;

    const __bf16* Wb = W2T + (size_t)e * (size_t)(D_DIM * H_DIM);
    const __bf16* gA[2]; const __bf16* gB[2];
#pragma unroll
    for (int j = 0; j < 2; ++j) {
        int rr = (w*2 + j) * 16 + (l >> 2);
        gA[j] = hbuf + (size_t)(row0 + rr) * H_DIM + part * 8;
        gB[j] = Wb + (size_t)(n0 + rr) * H_DIM + part * 8;
    }
    char* ldsA0 = smem + (w*2 + 0) * 1024;
    char* ldsA1 = smem + (w*2 + 1) * 1024;
    char* ldsB0 = smem + 8192 + (w*2 + 0) * 1024;
    char* ldsB1 = smem + 8192 + (w*2 + 1) * 1024;

    const int r = l & 15, q = l >> 4;
    const int wm = w & 1, wn = w >> 1;

    f32x4 acc[4][4];
#pragma unroll
    for (int mi = 0; mi < 4; ++mi)
#pragma unroll
        for (int ni = 0; ni < 4; ++ni) acc[mi][ni] = (f32x4){0.f, 0.f, 0.f, 0.f};

    for (int k0 = 0; k0 < H_DIM; k0 += 32) {
        gload_lds16(gA[0] + k0, ldsA0);
        gload_lds16(gA[1] + k0, ldsA1);
        gload_lds16(gB[0] + k0, ldsB0);
        gload_lds16(gB[1] + k0, ldsB1);
        __syncthreads();

        bf16x8 av[4], bv[4];
#pragma unroll
        for (int mi = 0; mi < 4; ++mi)
            av[mi] = *(const bf16x8*)(smem + ((wm*64 + mi*16 + r) * 64 + q * 16));
#pragma unroll
        for (int ni = 0; ni < 4; ++ni)
            bv[ni] = *(const bf16x8*)(smem + 8192 + ((wn*64 + ni*16 + r) * 64 + q * 16));
#pragma unroll
        for (int mi = 0; mi < 4; ++mi)
#pragma unroll
            for (int ni = 0; ni < 4; ++ni)
                acc[mi][ni] = __builtin_amdgcn_mfma_f32_16x16x32_bf16(av[mi], bv[ni], acc[mi][ni], 0, 0, 0);
        __syncthreads();
    }

    const float* b2e = b2 + (size_t)e * D_DIM;
    float bb[4];
#pragma unroll
    for (int ni = 0; ni < 4; ++ni) bb[ni] = b2e[n0 + wn*64 + ni*16 + r];
#pragma unroll
    for (int mi = 0; mi < 4; ++mi)
#pragma unroll
        for (int reg = 0; reg < 4; ++reg) {
            int row = row0 + wm*64 + mi*16 + q*4 + reg;
            __bf16* yrow = ybuf + (size_t)row * D_DIM + n0 + wn*64;
#pragma unroll
            for (int ni = 0; ni < 4; ++ni)
                yrow[ni*16 + r] = (__bf16)(acc[mi][ni][reg] + bb[ni]);
        }
}

// ---------------- combine: out[t] = s0*y[r0] + s1*y[r1] ----------------
__global__ __launch_bounds__(256) void k_combine(
    const __bf16* __restrict__ ybuf, const int* __restrict__ rowidx,
    const float* __restrict__ topk_s, float* __restrict__ out)
{
    const int t = blockIdx.x;
    const int d0 = threadIdx.x * 4;
    const int r0 = rowidx[t*2+0], r1 = rowidx[t*2+1];
    const float s0 = topk_s[t*2+0], s1 = topk_s[t*2+1];
    bf16x4 y0 = *(const bf16x4*)(ybuf + (size_t)r0 * D_DIM + d0);
    bf16x4 y1 = *(const bf16x4*)(ybuf + (size_t)r1 * D_DIM + d0);
    float4 o;
    o.x = s0 * (float)y0[0] + s1 * (float)y1[0];
    o.y = s0 * (float)y0[1] + s1 * (float)y1[1];
    o.z = s0 * (float)y0[2] + s1 * (float)y1[2];
    o.w = s0 * (float)y0[3] + s1 * (float)y1[3];
    *(float4*)(out + (size_t)t * D_DIM + d0) = o;
}

extern "C" void kernel_launch(void* const* d_in, const int* in_sizes, int n_in,
                              void* d_out, int out_size, void* d_ws, size_t ws_size,
                              hipStream_t stream) {
    const float* x  = (const float*)d_in[0];
    const float* Wg = (const float*)d_in[1];
    const float* W1 = (const float*)d_in[2];
    const float* b1 = (const float*)d_in[3];
    const float* W2 = (const float*)d_in[4];
    const float* b2 = (const float*)d_in[5];
    float* out = (float*)d_out;
    char* ws = (char*)d_ws;

    int*   mbTot  = (int*)  (ws + OFF_MBTOT);
    int*   mb2e   = (int*)  (ws + OFF_MB2E);
    int*   mbrow0 = (int*)  (ws + OFF_MBROW0);
    int*   topk_e = (int*)  (ws + OFF_TOPKE);
    float* topk_s = (float*)(ws + OFF_TOPKS);
    int*   tok    = (int*)  (ws + OFF_TOK);
    int*   rowidx = (int*)  (ws + OFF_ROWIDX);
    __bf16* xb   = (__bf16*)(ws + OFF_XB);
    __bf16* W1T  = (__bf16*)(ws + OFF_W1T);
    __bf16* W2T  = (__bf16*)(ws + OFF_W2T);
    __bf16* hbuf = (__bf16*)(ws + OFF_HBUF);
    __bf16* ybuf = (__bf16*)(ws + OFF_YBUF);

    // zero tok (pad rows -> tok=0). rowidx/mb tables fully written by k_sort.
    hipMemsetAsync(ws + OFF_TOK, 0, MAX_ROWS * sizeof(int), stream);

    k_router_cvt<<<T_TOK/4, 256, 0, stream>>>(x, Wg, xb, topk_e, topk_s);
    k_sort      <<<1, 512, 0, stream>>>(topk_e, mbTot, mb2e, mbrow0, tok, rowidx);
    k_transpose <<<dim3(D_DIM/64, H_DIM/64, E_NUM), 256, 0, stream>>>(W1, W1T, D_DIM, H_DIM);
    k_transpose <<<dim3(H_DIM/64, D_DIM/64, E_NUM), 256, 0, stream>>>(W2, W2T, H_DIM, D_DIM);

    k_gemm1<<<dim3(MAX_MB, H_DIM/128), 256, 0, stream>>>(xb, W1T, b1, tok, mb2e, mbrow0, mbTot, hbuf);
    k_gemm2<<<dim3(MAX_MB, D_DIM/128), 256, 0, stream>>>(hbuf, W2T, b2, mb2e, mbrow0, mbTot, ybuf);
    k_combine<<<T_TOK, 256, 0, stream>>>(ybuf, rowidx, topk_s, out);
}

// Round 4
// 436.341 us; speedup vs baseline: 1.6563x; 1.0034x over previous
//
#include <hip/hip_runtime.h>
#include <hip/hip_bf16.h>

typedef __bf16 bf16x8 __attribute__((ext_vector_type(8)));
typedef __bf16 bf16x4 __attribute__((ext_vector_type(4)));
typedef float  f32x4  __attribute__((ext_vector_type(4)));

#define T_TOK    8192
#define D_DIM    1024
#define H_DIM    2048
#define E_NUM    8
#define MAX_MB   136      // sum ceil(n_e/128) <= 8 + 16384/128 = 136
#define MAX_ROWS 17408    // 136*128

// ---- workspace layout (bytes) ----
#define OFF_MBTOT   512
#define OFF_MB2E    1024
#define OFF_MBROW0  2048
#define OFF_TOPKE   4096            // 16384 ints  -> ends 69632
#define OFF_TOPKS   69632           // 16384 float -> ends 135168
#define OFF_TOK     135168          // 17408 ints  -> ends 204800
#define OFF_ROWIDX  204800          // 16384 ints  -> ends 270336
#define OFF_XB      (1u<<20)                    // 8192*1024*2  = 16 MiB
#define OFF_W1T     (18u*1024*1024)             // 8*2048*1024*2 = 32 MiB -> ends 50 MiB
#define OFF_W2T     (50u*1024*1024)             // 8*1024*2048*2 = 32 MiB -> ends 82 MiB
#define OFF_HBUF    (82u*1024*1024)             // 17408*2048*2  = 68 MiB -> ends 150 MiB
// ybuf bf16 [17408][1024] = 34 MiB overlaid on xb+W1T (both dead after gemm1)
#define OFF_YBUF    OFF_XB

__device__ __forceinline__ void gload_lds16(const void* g, void* l) {
    __builtin_amdgcn_global_load_lds(
        (const __attribute__((address_space(1))) void*)g,
        (__attribute__((address_space(3))) void*)l, 16, 0, 0);
}

// ---------------- fused router (+ fp32->bf16 convert of x), NO atomics ----------------
__global__ __launch_bounds__(256) void k_router_cvt(
    const float* __restrict__ x, const float* __restrict__ Wg,
    __bf16* __restrict__ xb, int* __restrict__ topk_e, float* __restrict__ topk_s)
{
    __shared__ float wgT[E_NUM][1032];   // padded stride
    const int tid = threadIdx.x;
#pragma unroll
    for (int i = 0; i < 32; ++i) {
        int f = tid + i * 256;           // coalesced read of Wg[1024][8]
        wgT[f & 7][f >> 3] = Wg[f];
    }
    __syncthreads();

    const int wave = tid >> 6, lane = tid & 63;
    const int t = blockIdx.x * 4 + wave;
    const float* xr = x + (size_t)t * D_DIM;
    __bf16* xbr = xb + (size_t)t * D_DIM;

    float acc[E_NUM];
#pragma unroll
    for (int e = 0; e < E_NUM; ++e) acc[e] = 0.f;

#pragma unroll
    for (int j = 0; j < 4; ++j) {
        const int d0 = lane * 4 + j * 256;
        float4 xv = *(const float4*)(xr + d0);
        bf16x4 o = { (__bf16)xv.x, (__bf16)xv.y, (__bf16)xv.z, (__bf16)xv.w };
        *(bf16x4*)(xbr + d0) = o;
#pragma unroll
        for (int e = 0; e < E_NUM; ++e) {
            float4 wv = *(const float4*)&wgT[e][d0];
            acc[e] += xv.x * wv.x + xv.y * wv.y + xv.z * wv.z + xv.w * wv.w;
        }
    }
#pragma unroll
    for (int off = 32; off >= 1; off >>= 1)
#pragma unroll
        for (int e = 0; e < E_NUM; ++e) acc[e] += __shfl_xor(acc[e], off, 64);

    if (lane == 0) {
        int e0 = 0; float v0 = acc[0];
#pragma unroll
        for (int e = 1; e < E_NUM; ++e) if (acc[e] > v0) { v0 = acc[e]; e0 = e; }
        int e1 = -1; float v1 = -1e30f;
#pragma unroll
        for (int e = 0; e < E_NUM; ++e) if (e != e0 && acc[e] > v1) { v1 = acc[e]; e1 = e; }
        float s0 = 1.f / (1.f + __expf(v1 - v0));  // renormalized top-2 softmax
        float s1 = 1.f - s0;
        topk_e[t*2+0] = e0; topk_e[t*2+1] = e1;
        topk_s[t*2+0] = s0; topk_s[t*2+1] = s1;
    }
}

// ---------------- single-block counting sort: counts, offsets, mb tables, tok, rowidx ----------------
#define SORT_T 256
__global__ __launch_bounds__(512) void k_sort(
    const int* __restrict__ topk_e,
    int* __restrict__ mbTot, int* __restrict__ mb2e, int* __restrict__ mbrow0,
    int* __restrict__ tok, int* __restrict__ rowidx)
{
    __shared__ int lcnt[E_NUM][SORT_T];
    __shared__ int base[E_NUM];
    __shared__ int etot[E_NUM];
    const int tid = threadIdx.x;

    if (tid < SORT_T) {
        int c[E_NUM];
#pragma unroll
        for (int e = 0; e < E_NUM; ++e) c[e] = 0;
        const int4* p = (const int4*)(topk_e + tid * 64);
#pragma unroll
        for (int i = 0; i < 16; ++i) {
            int4 v = p[i];
            c[v.x]++; c[v.y]++; c[v.z]++; c[v.w]++;
        }
#pragma unroll
        for (int e = 0; e < E_NUM; ++e) lcnt[e][tid] = c[e];
    }
    __syncthreads();

    {
        const int w = tid >> 6, l = tid & 63;
        int v0 = lcnt[w][l*4+0], v1 = lcnt[w][l*4+1], v2 = lcnt[w][l*4+2], v3 = lcnt[w][l*4+3];
        int s = v0 + v1 + v2 + v3;
        int inc = s;
#pragma unroll
        for (int off = 1; off < 64; off <<= 1) {
            int o = __shfl_up(inc, off, 64);
            if (l >= off) inc += o;
        }
        int exc = inc - s;
        lcnt[w][l*4+0] = exc;
        lcnt[w][l*4+1] = exc + v0;
        lcnt[w][l*4+2] = exc + v0 + v1;
        lcnt[w][l*4+3] = exc + v0 + v1 + v2;
        if (l == 63) etot[w] = inc;
    }
    __syncthreads();

    if (tid == 0) {
        int row = 0, mb = 0;
        for (int e = 0; e < E_NUM; ++e) {
            base[e] = row;
            int nb = (etot[e] + 127) >> 7;
            for (int b = 0; b < nb; ++b) { mb2e[mb] = e; mbrow0[mb] = row + b*128; ++mb; }
            row += nb * 128;
        }
        mbTot[0] = mb;
    }
    __syncthreads();

    if (tid < SORT_T) {
        int c[E_NUM];
#pragma unroll
        for (int e = 0; e < E_NUM; ++e) c[e] = base[e] + lcnt[e][tid];
        const int4* p = (const int4*)(topk_e + tid * 64);
#pragma unroll
        for (int i = 0; i < 16; ++i) {
            int4 v = p[i];
            int j0 = tid * 64 + i * 4;
            int r;
            r = c[v.x]++; tok[r] = (j0+0) >> 1; rowidx[j0+0] = r;
            r = c[v.y]++; tok[r] = (j0+1) >> 1; rowidx[j0+1] = r;
            r = c[v.z]++; tok[r] = (j0+2) >> 1; rowidx[j0+2] = r;
            r = c[v.w]++; tok[r] = (j0+3) >> 1; rowidx[j0+3] = r;
        }
    }
}

// ---------------- transpose+convert: in [E][R][C] f32 -> out [E][C][R] bf16 ----------------
__global__ __launch_bounds__(256) void k_transpose(
    const float* __restrict__ in, __bf16* __restrict__ out, int R, int C)
{
    __shared__ float tile[64][65];
    const int e = blockIdx.z;
    const float* inp = in + (size_t)e * R * C;
    __bf16* outp = out + (size_t)e * R * C;
    const int r0 = blockIdx.x * 64, c0 = blockIdx.y * 64;
    const int c = threadIdx.x & 63, rr = threadIdx.x >> 6;
#pragma unroll
    for (int i = 0; i < 16; ++i) {
        int r = rr + i * 4;
        tile[r][c] = inp[(size_t)(r0 + r) * C + c0 + c];
    }
    __syncthreads();
#pragma unroll
    for (int i = 0; i < 16; ++i) {
        int cc = rr + i * 4;
        outp[(size_t)(c0 + cc) * R + r0 + c] = (__bf16)tile[c][cc];
    }
}

// ---------------- GEMM1: h = relu(gather(x) @ W1[e] + b1[e]) -> hbuf (bf16) ----------------
// LDS layout: row-major [128][32]bf16 with XOR swizzle: 16B chunk c of row m at
// position c ^ ((m>>1)&3).  2 lanes/bank-group per quarter-wave -> conflict-free.
__global__ __launch_bounds__(256) void k_gemm1(
    const __bf16* __restrict__ xb, const __bf16* __restrict__ W1T,
    const float* __restrict__ b1, const int* __restrict__ tok,
    const int* __restrict__ mb2e, const int* __restrict__ mbrow0,
    const int* __restrict__ mbTot, __bf16* __restrict__ hbuf)
{
    if ((int)blockIdx.x >= *mbTot) return;
    const int e    = mb2e[blockIdx.x];
    const int row0 = mbrow0[blockIdx.x];
    const int n0   = blockIdx.y * 128;

    __shared__ __align__(16) char smem[16384];

    const int tid = threadIdx.x;
    const int w = tid >> 6, l = tid & 63;
    const int part = (l & 3) ^ ((l >> 3) & 3);   // swizzled global 16B-chunk

    const __bf16* Wb = W1T + (size_t)e * (size_t)(H_DIM * D_DIM);
    const __bf16* gA[2]; const __bf16* gB[2];
#pragma unroll
    for (int j = 0; j < 2; ++j) {
        int rr = (w*2 + j) * 16 + (l >> 2);        // 0..127
        int t  = tok[row0 + rr];
        gA[j] = xb + (size_t)t * D_DIM + part * 8;
        gB[j] = Wb + (size_t)(n0 + rr) * D_DIM + part * 8;
    }
    char* ldsA0 = smem + (w*2 + 0) * 1024;
    char* ldsA1 = smem + (w*2 + 1) * 1024;
    char* ldsB0 = smem + 8192 + (w*2 + 0) * 1024;
    char* ldsB1 = smem + 8192 + (w*2 + 1) * 1024;

    const int r = l & 15, q = l >> 4;
    const int wm = w & 1, wn = w >> 1;
    const int qx = (q ^ ((r >> 1) & 3)) * 16;    // swizzled chunk offset for reads

    f32x4 acc[4][4];
#pragma unroll
    for (int mi = 0; mi < 4; ++mi)
#pragma unroll
        for (int ni = 0; ni < 4; ++ni) acc[mi][ni] = (f32x4){0.f, 0.f, 0.f, 0.f};

    for (int k0 = 0; k0 < D_DIM; k0 += 32) {
        gload_lds16(gA[0] + k0, ldsA0);
        gload_lds16(gA[1] + k0, ldsA1);
        gload_lds16(gB[0] + k0, ldsB0);
        gload_lds16(gB[1] + k0, ldsB1);
        __syncthreads();

        bf16x8 av[4], bv[4];
#pragma unroll
        for (int mi = 0; mi < 4; ++mi)
            av[mi] = *(const bf16x8*)(smem + ((wm*64 + mi*16 + r) * 64 + qx));
#pragma unroll
        for (int ni = 0; ni < 4; ++ni)
            bv[ni] = *(const bf16x8*)(smem + 8192 + ((wn*64 + ni*16 + r) * 64 + qx));
#pragma unroll
        for (int mi = 0; mi < 4; ++mi)
#pragma unroll
            for (int ni = 0; ni < 4; ++ni)
                acc[mi][ni] = __builtin_amdgcn_mfma_f32_16x16x32_bf16(av[mi], bv[ni], acc[mi][ni], 0, 0, 0);
        __syncthreads();
    }

    const float* b1e = b1 + (size_t)e * H_DIM;
    float bb[4];
#pragma unroll
    for (int ni = 0; ni < 4; ++ni) bb[ni] = b1e[n0 + wn*64 + ni*16 + r];
#pragma unroll
    for (int mi = 0; mi < 4; ++mi)
#pragma unroll
        for (int reg = 0; reg < 4; ++reg) {
            int m = wm*64 + mi*16 + q*4 + reg;
            __bf16* hrow = hbuf + (size_t)(row0 + m) * H_DIM + n0 + wn*64;
#pragma unroll
            for (int ni = 0; ni < 4; ++ni) {
                float v = acc[mi][ni][reg] + bb[ni];
                hrow[ni*16 + r] = (__bf16)fmaxf(v, 0.f);
            }
        }
}

// ---------------- GEMM2: ybuf[row] = hbuf[row] @ W2[e] + b2[e]  (bf16, ungated) ----------------
__global__ __launch_bounds__(256) void k_gemm2(
    const __bf16* __restrict__ hbuf, const __bf16* __restrict__ W2T,
    const float* __restrict__ b2, const int* __restrict__ mb2e,
    const int* __restrict__ mbrow0, const int* __restrict__ mbTot,
    __bf16* __restrict__ ybuf)
{
    if ((int)blockIdx.x >= *mbTot) return;
    const int e    = mb2e[blockIdx.x];
    const int row0 = mbrow0[blockIdx.x];
    const int n0   = blockIdx.y * 128;

    __shared__ __align__(16) char smem[16384];

    const int tid = threadIdx.x;
    const int w = tid >> 6, l = tid & 63;
    const int part = (l & 3) ^ ((l >> 3) & 3);   // swizzled global 16B-chunk

    const __bf16* Wb = W2T + (size_t)e * (size_t)(D_DIM * H_DIM);
    const __bf16* gA[2]; const __bf16* gB[2];
#pragma unroll
    for (int j = 0; j < 2; ++j) {
        int rr = (w*2 + j) * 16 + (l >> 2);
        gA[j] = hbuf + (size_t)(row0 + rr) * H_DIM + part * 8;
        gB[j] = Wb + (size_t)(n0 + rr) * H_DIM + part * 8;
    }
    char* ldsA0 = smem + (w*2 + 0) * 1024;
    char* ldsA1 = smem + (w*2 + 1) * 1024;
    char* ldsB0 = smem + 8192 + (w*2 + 0) * 1024;
    char* ldsB1 = smem + 8192 + (w*2 + 1) * 1024;

    const int r = l & 15, q = l >> 4;
    const int wm = w & 1, wn = w >> 1;
    const int qx = (q ^ ((r >> 1) & 3)) * 16;

    f32x4 acc[4][4];
#pragma unroll
    for (int mi = 0; mi < 4; ++mi)
#pragma unroll
        for (int ni = 0; ni < 4; ++ni) acc[mi][ni] = (f32x4){0.f, 0.f, 0.f, 0.f};

    for (int k0 = 0; k0 < H_DIM; k0 += 32) {
        gload_lds16(gA[0] + k0, ldsA0);
        gload_lds16(gA[1] + k0, ldsA1);
        gload_lds16(gB[0] + k0, ldsB0);
        gload_lds16(gB[1] + k0, ldsB1);
        __syncthreads();

        bf16x8 av[4], bv[4];
#pragma unroll
        for (int mi = 0; mi < 4; ++mi)
            av[mi] = *(const bf16x8*)(smem + ((wm*64 + mi*16 + r) * 64 + qx));
#pragma unroll
        for (int ni = 0; ni < 4; ++ni)
            bv[ni] = *(const bf16x8*)(smem + 8192 + ((wn*64 + ni*16 + r) * 64 + qx));
#pragma unroll
        for (int mi = 0; mi < 4; ++mi)
#pragma unroll
            for (int ni = 0; ni < 4; ++ni)
                acc[mi][ni] = __builtin_amdgcn_mfma_f32_16x16x32_bf16(av[mi], bv[ni], acc[mi][ni], 0, 0, 0);
        __syncthreads();
    }

    const float* b2e = b2 + (size_t)e * D_DIM;
    float bb[4];
#pragma unroll
    for (int ni = 0; ni < 4; ++ni) bb[ni] = b2e[n0 + wn*64 + ni*16 + r];
#pragma unroll
    for (int mi = 0; mi < 4; ++mi)
#pragma unroll
        for (int reg = 0; reg < 4; ++reg) {
            int row = row0 + wm*64 + mi*16 + q*4 + reg;
            __bf16* yrow = ybuf + (size_t)row * D_DIM + n0 + wn*64;
#pragma unroll
            for (int ni = 0; ni < 4; ++ni)
                yrow[ni*16 + r] = (__bf16)(acc[mi][ni][reg] + bb[ni]);
        }
}

// ---------------- combine: out[t] = s0*y[r0] + s1*y[r1] ----------------
__global__ __launch_bounds__(256) void k_combine(
    const __bf16* __restrict__ ybuf, const int* __restrict__ rowidx,
    const float* __restrict__ topk_s, float* __restrict__ out)
{
    const int t = blockIdx.x;
    const int d0 = threadIdx.x * 4;
    const int r0 = rowidx[t*2+0], r1 = rowidx[t*2+1];
    const float s0 = topk_s[t*2+0], s1 = topk_s[t*2+1];
    bf16x4 y0 = *(const bf16x4*)(ybuf + (size_t)r0 * D_DIM + d0);
    bf16x4 y1 = *(const bf16x4*)(ybuf + (size_t)r1 * D_DIM + d0);
    float4 o;
    o.x = s0 * (float)y0[0] + s1 * (float)y1[0];
    o.y = s0 * (float)y0[1] + s1 * (float)y1[1];
    o.z = s0 * (float)y0[2] + s1 * (float)y1[2];
    o.w = s0 * (float)y0[3] + s1 * (float)y1[3];
    *(float4*)(out + (size_t)t * D_DIM + d0) = o;
}

extern "C" void kernel_launch(void* const* d_in, const int* in_sizes, int n_in,
                              void* d_out, int out_size, void* d_ws, size_t ws_size,
                              hipStream_t stream) {
    const float* x  = (const float*)d_in[0];
    const float* Wg = (const float*)d_in[1];
    const float* W1 = (const float*)d_in[2];
    const float* b1 = (const float*)d_in[3];
    const float* W2 = (const float*)d_in[4];
    const float* b2 = (const float*)d_in[5];
    float* out = (float*)d_out;
    char* ws = (char*)d_ws;

    int*   mbTot  = (int*)  (ws + OFF_MBTOT);
    int*   mb2e   = (int*)  (ws + OFF_MB2E);
    int*   mbrow0 = (int*)  (ws + OFF_MBROW0);
    int*   topk_e = (int*)  (ws + OFF_TOPKE);
    float* topk_s = (float*)(ws + OFF_TOPKS);
    int*   tok    = (int*)  (ws + OFF_TOK);
    int*   rowidx = (int*)  (ws + OFF_ROWIDX);
    __bf16* xb   = (__bf16*)(ws + OFF_XB);
    __bf16* W1T  = (__bf16*)(ws + OFF_W1T);
    __bf16* W2T  = (__bf16*)(ws + OFF_W2T);
    __bf16* hbuf = (__bf16*)(ws + OFF_HBUF);
    __bf16* ybuf = (__bf16*)(ws + OFF_YBUF);

    // zero tok (pad rows -> tok=0). rowidx/mb tables fully written by k_sort.
    hipMemsetAsync(ws + OFF_TOK, 0, MAX_ROWS * sizeof(int), stream);

    k_router_cvt<<<T_TOK/4, 256, 0, stream>>>(x, Wg, xb, topk_e, topk_s);
    k_sort      <<<1, 512, 0, stream>>>(topk_e, mbTot, mb2e, mbrow0, tok, rowidx);
    k_transpose <<<dim3(D_DIM/64, H_DIM/64, E_NUM), 256, 0, stream>>>(W1, W1T, D_DIM, H_DIM);
    k_transpose <<<dim3(H_DIM/64, D_DIM/64, E_NUM), 256, 0, stream>>>(W2, W2T, H_DIM, D_DIM);

    k_gemm1<<<dim3(MAX_MB, H_DIM/128), 256, 0, stream>>>(xb, W1T, b1, tok, mb2e, mbrow0, mbTot, hbuf);
    k_gemm2<<<dim3(MAX_MB, D_DIM/128), 256, 0, stream>>>(hbuf, W2T, b2, mb2e, mbrow0, mbTot, ybuf);
    k_combine<<<T_TOK, 256, 0, stream>>>(ybuf, rowidx, topk_s, out);
}

// Round 5
// 430.691 us; speedup vs baseline: 1.6780x; 1.0131x over previous
//
#include <hip/hip_runtime.h>
#include <hip/hip_bf16.h>

typedef __bf16 bf16x8 __attribute__((ext_vector_type(8)));
typedef __bf16 bf16x4 __attribute__((ext_vector_type(4)));
typedef float  f32x4  __attribute__((ext_vector_type(4)));

#define T_TOK    8192
#define D_DIM    1024
#define H_DIM    2048
#define E_NUM    8
#define MAX_MB   136      // 17*8; sum ceil(n_e/128) <= 8 + 16384/128 = 136
#define MAX_ROWS 17408    // 136*128

// ---- workspace layout (bytes) ----
#define OFF_MBTOT   512
#define OFF_MB2E    1024
#define OFF_MBROW0  2048
#define OFF_TOPKE   4096            // 16384 ints  -> ends 69632
#define OFF_TOPKS   69632           // 16384 float -> ends 135168
#define OFF_TOK     135168          // 17408 ints  -> ends 204800
#define OFF_ROWIDX  204800          // 16384 ints  -> ends 270336
#define OFF_XB      (1u<<20)                    // 8192*1024*2  = 16 MiB
#define OFF_W1T     (18u*1024*1024)             // 8*2048*1024*2 = 32 MiB -> ends 50 MiB
#define OFF_W2T     (50u*1024*1024)             // 8*1024*2048*2 = 32 MiB -> ends 82 MiB
#define OFF_HBUF    (82u*1024*1024)             // 17408*2048*2  = 68 MiB -> ends 150 MiB
// ybuf bf16 [17408][1024] = 34 MiB overlaid on xb+W1T (both dead after gemm1)
#define OFF_YBUF    OFF_XB

__device__ __forceinline__ void gload_lds16(const void* g, void* l) {
    __builtin_amdgcn_global_load_lds(
        (const __attribute__((address_space(1))) void*)g,
        (__attribute__((address_space(3))) void*)l, 16, 0, 0);
}

// ---------------- fused router (+ fp32->bf16 convert of x), NO atomics ----------------
__global__ __launch_bounds__(256) void k_router_cvt(
    const float* __restrict__ x, const float* __restrict__ Wg,
    __bf16* __restrict__ xb, int* __restrict__ topk_e, float* __restrict__ topk_s)
{
    __shared__ float wgT[E_NUM][1032];   // padded stride
    const int tid = threadIdx.x;
#pragma unroll
    for (int i = 0; i < 32; ++i) {
        int f = tid + i * 256;           // coalesced read of Wg[1024][8]
        wgT[f & 7][f >> 3] = Wg[f];
    }
    __syncthreads();

    const int wave = tid >> 6, lane = tid & 63;
    const int t = blockIdx.x * 4 + wave;
    const float* xr = x + (size_t)t * D_DIM;
    __bf16* xbr = xb + (size_t)t * D_DIM;

    float acc[E_NUM];
#pragma unroll
    for (int e = 0; e < E_NUM; ++e) acc[e] = 0.f;

#pragma unroll
    for (int j = 0; j < 4; ++j) {
        const int d0 = lane * 4 + j * 256;
        float4 xv = *(const float4*)(xr + d0);
        bf16x4 o = { (__bf16)xv.x, (__bf16)xv.y, (__bf16)xv.z, (__bf16)xv.w };
        *(bf16x4*)(xbr + d0) = o;
#pragma unroll
        for (int e = 0; e < E_NUM; ++e) {
            float4 wv = *(const float4*)&wgT[e][d0];
            acc[e] += xv.x * wv.x + xv.y * wv.y + xv.z * wv.z + xv.w * wv.w;
        }
    }
#pragma unroll
    for (int off = 32; off >= 1; off >>= 1)
#pragma unroll
        for (int e = 0; e < E_NUM; ++e) acc[e] += __shfl_xor(acc[e], off, 64);

    if (lane == 0) {
        int e0 = 0; float v0 = acc[0];
#pragma unroll
        for (int e = 1; e < E_NUM; ++e) if (acc[e] > v0) { v0 = acc[e]; e0 = e; }
        int e1 = -1; float v1 = -1e30f;
#pragma unroll
        for (int e = 0; e < E_NUM; ++e) if (e != e0 && acc[e] > v1) { v1 = acc[e]; e1 = e; }
        float s0 = 1.f / (1.f + __expf(v1 - v0));  // renormalized top-2 softmax
        float s1 = 1.f - s0;
        topk_e[t*2+0] = e0; topk_e[t*2+1] = e1;
        topk_s[t*2+0] = s0; topk_s[t*2+1] = s1;
    }
}

// ---------------- single-block counting sort ----------------
// All runtime-indexed counters live in LDS (NOT registers -> no scratch spill).
#define SORT_T 256
__global__ __launch_bounds__(512) void k_sort(
    const int* __restrict__ topk_e,
    int* __restrict__ mbTot, int* __restrict__ mb2e, int* __restrict__ mbrow0,
    int* __restrict__ tok, int* __restrict__ rowidx)
{
    __shared__ int lcnt[E_NUM][SORT_T];   // histogram -> exclusive offsets -> cursors
    __shared__ int base[E_NUM];
    __shared__ int etot[E_NUM];
    const int tid = threadIdx.x;

    if (tid < SORT_T) {
#pragma unroll
        for (int e = 0; e < E_NUM; ++e) lcnt[e][tid] = 0;
    }
    __syncthreads();

    // phase 1: per-thread histogram of 64 entries each, counters in LDS
    if (tid < SORT_T) {
        const int4* p = (const int4*)(topk_e + tid * 64);
#pragma unroll
        for (int i = 0; i < 16; ++i) {
            int4 v = p[i];
            lcnt[v.x][tid]++; lcnt[v.y][tid]++; lcnt[v.z][tid]++; lcnt[v.w][tid]++;
        }
    }
    __syncthreads();

    // phase 2: wave w scans expert w's 256 thread-counts (exclusive)
    {
        const int w = tid >> 6, l = tid & 63;
        int v0 = lcnt[w][l*4+0], v1 = lcnt[w][l*4+1], v2 = lcnt[w][l*4+2], v3 = lcnt[w][l*4+3];
        int s = v0 + v1 + v2 + v3;
        int inc = s;
#pragma unroll
        for (int off = 1; off < 64; off <<= 1) {
            int o = __shfl_up(inc, off, 64);
            if (l >= off) inc += o;
        }
        int exc = inc - s;
        lcnt[w][l*4+0] = exc;
        lcnt[w][l*4+1] = exc + v0;
        lcnt[w][l*4+2] = exc + v0 + v1;
        lcnt[w][l*4+3] = exc + v0 + v1 + v2;
        if (l == 63) etot[w] = inc;
    }
    __syncthreads();

    // phase 3: serial (8 experts) base rows + M-block tables
    if (tid == 0) {
        int row = 0, mb = 0;
        for (int e = 0; e < E_NUM; ++e) {
            base[e] = row;
            int nb = (etot[e] + 127) >> 7;
            for (int b = 0; b < nb; ++b) { mb2e[mb] = e; mbrow0[mb] = row + b*128; ++mb; }
            row += nb * 128;
        }
        mbTot[0] = mb;
    }
    __syncthreads();

    // phase 4: cursors = base + exclusive offset (in place), then placement via LDS RMW
    if (tid < SORT_T) {
#pragma unroll
        for (int e = 0; e < E_NUM; ++e) lcnt[e][tid] += base[e];
        const int4* p = (const int4*)(topk_e + tid * 64);
#pragma unroll
        for (int i = 0; i < 16; ++i) {
            int4 v = p[i];
            int j0 = tid * 64 + i * 4;
            int r;
            r = lcnt[v.x][tid]++; tok[r] = (j0+0) >> 1; rowidx[j0+0] = r;
            r = lcnt[v.y][tid]++; tok[r] = (j0+1) >> 1; rowidx[j0+1] = r;
            r = lcnt[v.z][tid]++; tok[r] = (j0+2) >> 1; rowidx[j0+2] = r;
            r = lcnt[v.w][tid]++; tok[r] = (j0+3) >> 1; rowidx[j0+3] = r;
        }
    }
}

// ---------------- transpose+convert: in [E][R][C] f32 -> out [E][C][R] bf16 ----------------
__global__ __launch_bounds__(256) void k_transpose(
    const float* __restrict__ in, __bf16* __restrict__ out, int R, int C)
{
    __shared__ float tile[64][65];
    const int e = blockIdx.z;
    const float* inp = in + (size_t)e * R * C;
    __bf16* outp = out + (size_t)e * R * C;
    const int r0 = blockIdx.x * 64, c0 = blockIdx.y * 64;
    const int c = threadIdx.x & 63, rr = threadIdx.x >> 6;
#pragma unroll
    for (int i = 0; i < 16; ++i) {
        int r = rr + i * 4;
        tile[r][c] = inp[(size_t)(r0 + r) * C + c0 + c];
    }
    __syncthreads();
#pragma unroll
    for (int i = 0; i < 16; ++i) {
        int cc = rr + i * 4;
        outp[(size_t)(c0 + cc) * R + r0 + c] = (__bf16)tile[c][cc];
    }
}

// ---------------- GEMM1: h = relu(gather(x) @ W1[e] + b1[e]) -> hbuf (bf16) ----------------
// 1-D grid with XCD-aware swizzle: all 16 n-blocks of one mb share id%8 (same XCD)
// and are temporally adjacent there -> A-tile served from that XCD's L2.
__global__ __launch_bounds__(256) void k_gemm1(
    const __bf16* __restrict__ xb, const __bf16* __restrict__ W1T,
    const float* __restrict__ b1, const int* __restrict__ tok,
    const int* __restrict__ mb2e, const int* __restrict__ mbrow0,
    const int* __restrict__ mbTot, __bf16* __restrict__ hbuf)
{
    const int id   = blockIdx.x;            // 0..2175
    const int xcd  = id & 7;
    const int j    = id >> 3;               // 0..271
    const int nblk = j & 15;                // 0..15
    const int mb   = (j >> 4) * 8 + xcd;    // 0..135
    if (mb >= *mbTot) return;
    const int e    = mb2e[mb];
    const int row0 = mbrow0[mb];
    const int n0   = nblk * 128;

    __shared__ __align__(16) char smem[16384];

    const int tid = threadIdx.x;
    const int w = tid >> 6, l = tid & 63;
    const int part = (l & 3) ^ ((l >> 3) & 3);   // swizzled global 16B-chunk

    const __bf16* Wb = W1T + (size_t)e * (size_t)(H_DIM * D_DIM);
    const __bf16* gA[2]; const __bf16* gB[2];
#pragma unroll
    for (int jj = 0; jj < 2; ++jj) {
        int rr = (w*2 + jj) * 16 + (l >> 2);       // 0..127
        int t  = tok[row0 + rr];
        gA[jj] = xb + (size_t)t * D_DIM + part * 8;
        gB[jj] = Wb + (size_t)(n0 + rr) * D_DIM + part * 8;
    }
    char* ldsA0 = smem + (w*2 + 0) * 1024;
    char* ldsA1 = smem + (w*2 + 1) * 1024;
    char* ldsB0 = smem + 8192 + (w*2 + 0) * 1024;
    char* ldsB1 = smem + 8192 + (w*2 + 1) * 1024;

    const int r = l & 15, q = l >> 4;
    const int wm = w & 1, wn = w >> 1;
    const int qx = (q ^ ((r >> 1) & 3)) * 16;    // swizzled chunk offset for reads

    f32x4 acc[4][4];
#pragma unroll
    for (int mi = 0; mi < 4; ++mi)
#pragma unroll
        for (int ni = 0; ni < 4; ++ni) acc[mi][ni] = (f32x4){0.f, 0.f, 0.f, 0.f};

    for (int k0 = 0; k0 < D_DIM; k0 += 32) {
        gload_lds16(gA[0] + k0, ldsA0);
        gload_lds16(gA[1] + k0, ldsA1);
        gload_lds16(gB[0] + k0, ldsB0);
        gload_lds16(gB[1] + k0, ldsB1);
        __syncthreads();

        bf16x8 av[4], bv[4];
#pragma unroll
        for (int mi = 0; mi < 4; ++mi)
            av[mi] = *(const bf16x8*)(smem + ((wm*64 + mi*16 + r) * 64 + qx));
#pragma unroll
        for (int ni = 0; ni < 4; ++ni)
            bv[ni] = *(const bf16x8*)(smem + 8192 + ((wn*64 + ni*16 + r) * 64 + qx));
#pragma unroll
        for (int mi = 0; mi < 4; ++mi)
#pragma unroll
            for (int ni = 0; ni < 4; ++ni)
                acc[mi][ni] = __builtin_amdgcn_mfma_f32_16x16x32_bf16(av[mi], bv[ni], acc[mi][ni], 0, 0, 0);
        __syncthreads();
    }

    const float* b1e = b1 + (size_t)e * H_DIM;
    float bb[4];
#pragma unroll
    for (int ni = 0; ni < 4; ++ni) bb[ni] = b1e[n0 + wn*64 + ni*16 + r];
#pragma unroll
    for (int mi = 0; mi < 4; ++mi)
#pragma unroll
        for (int reg = 0; reg < 4; ++reg) {
            int m = wm*64 + mi*16 + q*4 + reg;
            __bf16* hrow = hbuf + (size_t)(row0 + m) * H_DIM + n0 + wn*64;
#pragma unroll
            for (int ni = 0; ni < 4; ++ni) {
                float v = acc[mi][ni][reg] + bb[ni];
                hrow[ni*16 + r] = (__bf16)fmaxf(v, 0.f);
            }
        }
}

// ---------------- GEMM2: ybuf[row] = hbuf[row] @ W2[e] + b2[e]  (bf16, ungated) ----------------
__global__ __launch_bounds__(256) void k_gemm2(
    const __bf16* __restrict__ hbuf, const __bf16* __restrict__ W2T,
    const float* __restrict__ b2, const int* __restrict__ mb2e,
    const int* __restrict__ mbrow0, const int* __restrict__ mbTot,
    __bf16* __restrict__ ybuf)
{
    const int id   = blockIdx.x;            // 0..1087
    const int xcd  = id & 7;
    const int j    = id >> 3;               // 0..135
    const int nblk = j & 7;                 // 0..7
    const int mb   = (j >> 3) * 8 + xcd;    // 0..135
    if (mb >= *mbTot) return;
    const int e    = mb2e[mb];
    const int row0 = mbrow0[mb];
    const int n0   = nblk * 128;

    __shared__ __align__(16) char smem[16384];

    const int tid = threadIdx.x;
    const int w = tid >> 6, l = tid & 63;
    const int part = (l & 3) ^ ((l >> 3) & 3);

    const __bf16* Wb = W2T + (size_t)e * (size_t)(D_DIM * H_DIM);
    const __bf16* gA[2]; const __bf16* gB[2];
#pragma unroll
    for (int jj = 0; jj < 2; ++jj) {
        int rr = (w*2 + jj) * 16 + (l >> 2);
        gA[jj] = hbuf + (size_t)(row0 + rr) * H_DIM + part * 8;
        gB[jj] = Wb + (size_t)(n0 + rr) * H_DIM + part * 8;
    }
    char* ldsA0 = smem + (w*2 + 0) * 1024;
    char* ldsA1 = smem + (w*2 + 1) * 1024;
    char* ldsB0 = smem + 8192 + (w*2 + 0) * 1024;
    char* ldsB1 = smem + 8192 + (w*2 + 1) * 1024;

    const int r = l & 15, q = l >> 4;
    const int wm = w & 1, wn = w >> 1;
    const int qx = (q ^ ((r >> 1) & 3)) * 16;

    f32x4 acc[4][4];
#pragma unroll
    for (int mi = 0; mi < 4; ++mi)
#pragma unroll
        for (int ni = 0; ni < 4; ++ni) acc[mi][ni] = (f32x4){0.f, 0.f, 0.f, 0.f};

    for (int k0 = 0; k0 < H_DIM; k0 += 32) {
        gload_lds16(gA[0] + k0, ldsA0);
        gload_lds16(gA[1] + k0, ldsA1);
        gload_lds16(gB[0] + k0, ldsB0);
        gload_lds16(gB[1] + k0, ldsB1);
        __syncthreads();

        bf16x8 av[4], bv[4];
#pragma unroll
        for (int mi = 0; mi < 4; ++mi)
            av[mi] = *(const bf16x8*)(smem + ((wm*64 + mi*16 + r) * 64 + qx));
#pragma unroll
        for (int ni = 0; ni < 4; ++ni)
            bv[ni] = *(const bf16x8*)(smem + 8192 + ((wn*64 + ni*16 + r) * 64 + qx));
#pragma unroll
        for (int mi = 0; mi < 4; ++mi)
#pragma unroll
            for (int ni = 0; ni < 4; ++ni)
                acc[mi][ni] = __builtin_amdgcn_mfma_f32_16x16x32_bf16(av[mi], bv[ni], acc[mi][ni], 0, 0, 0);
        __syncthreads();
    }

    const float* b2e = b2 + (size_t)e * D_DIM;
    float bb[4];
#pragma unroll
    for (int ni = 0; ni < 4; ++ni) bb[ni] = b2e[n0 + wn*64 + ni*16 + r];
#pragma unroll
    for (int mi = 0; mi < 4; ++mi)
#pragma unroll
        for (int reg = 0; reg < 4; ++reg) {
            int row = row0 + wm*64 + mi*16 + q*4 + reg;
            __bf16* yrow = ybuf + (size_t)row * D_DIM + n0 + wn*64;
#pragma unroll
            for (int ni = 0; ni < 4; ++ni)
                yrow[ni*16 + r] = (__bf16)(acc[mi][ni][reg] + bb[ni]);
        }
}

// ---------------- combine: out[t] = s0*y[r0] + s1*y[r1] ----------------
__global__ __launch_bounds__(256) void k_combine(
    const __bf16* __restrict__ ybuf, const int* __restrict__ rowidx,
    const float* __restrict__ topk_s, float* __restrict__ out)
{
    const int t = blockIdx.x;
    const int d0 = threadIdx.x * 4;
    const int r0 = rowidx[t*2+0], r1 = rowidx[t*2+1];
    const float s0 = topk_s[t*2+0], s1 = topk_s[t*2+1];
    bf16x4 y0 = *(const bf16x4*)(ybuf + (size_t)r0 * D_DIM + d0);
    bf16x4 y1 = *(const bf16x4*)(ybuf + (size_t)r1 * D_DIM + d0);
    float4 o;
    o.x = s0 * (float)y0[0] + s1 * (float)y1[0];
    o.y = s0 * (float)y0[1] + s1 * (float)y1[1];
    o.z = s0 * (float)y0[2] + s1 * (float)y1[2];
    o.w = s0 * (float)y0[3] + s1 * (float)y1[3];
    *(float4*)(out + (size_t)t * D_DIM + d0) = o;
}

extern "C" void kernel_launch(void* const* d_in, const int* in_sizes, int n_in,
                              void* d_out, int out_size, void* d_ws, size_t ws_size,
                              hipStream_t stream) {
    const float* x  = (const float*)d_in[0];
    const float* Wg = (const float*)d_in[1];
    const float* W1 = (const float*)d_in[2];
    const float* b1 = (const float*)d_in[3];
    const float* W2 = (const float*)d_in[4];
    const float* b2 = (const float*)d_in[5];
    float* out = (float*)d_out;
    char* ws = (char*)d_ws;

    int*   mbTot  = (int*)  (ws + OFF_MBTOT);
    int*   mb2e   = (int*)  (ws + OFF_MB2E);
    int*   mbrow0 = (int*)  (ws + OFF_MBROW0);
    int*   topk_e = (int*)  (ws + OFF_TOPKE);
    float* topk_s = (float*)(ws + OFF_TOPKS);
    int*   tok    = (int*)  (ws + OFF_TOK);
    int*   rowidx = (int*)  (ws + OFF_ROWIDX);
    __bf16* xb   = (__bf16*)(ws + OFF_XB);
    __bf16* W1T  = (__bf16*)(ws + OFF_W1T);
    __bf16* W2T  = (__bf16*)(ws + OFF_W2T);
    __bf16* hbuf = (__bf16*)(ws + OFF_HBUF);
    __bf16* ybuf = (__bf16*)(ws + OFF_YBUF);

    // zero tok (pad rows -> tok=0). rowidx/mb tables fully written by k_sort.
    hipMemsetAsync(ws + OFF_TOK, 0, MAX_ROWS * sizeof(int), stream);

    k_router_cvt<<<T_TOK/4, 256, 0, stream>>>(x, Wg, xb, topk_e, topk_s);
    k_sort      <<<1, 512, 0, stream>>>(topk_e, mbTot, mb2e, mbrow0, tok, rowidx);
    k_transpose <<<dim3(D_DIM/64, H_DIM/64, E_NUM), 256, 0, stream>>>(W1, W1T, D_DIM, H_DIM);
    k_transpose <<<dim3(H_DIM/64, D_DIM/64, E_NUM), 256, 0, stream>>>(W2, W2T, H_DIM, D_DIM);

    k_gemm1<<<MAX_MB * (H_DIM/128), 256, 0, stream>>>(xb, W1T, b1, tok, mb2e, mbrow0, mbTot, hbuf);
    k_gemm2<<<MAX_MB * (D_DIM/128), 256, 0, stream>>>(hbuf, W2T, b2, mb2e, mbrow0, mbTot, ybuf);
    k_combine<<<T_TOK, 256, 0, stream>>>(ybuf, rowidx, topk_s, out);
}